// Round 1
// baseline (1079.269 us; speedup 1.0000x reference)
//
#include <hip/hip_runtime.h>

// Sizes
#define Gg   128
#define N1   512
#define FH   128
#define K1   256
#define K2   128
#define MAXD 160

__device__ inline float wredsum(float v) {
#pragma unroll
    for (int o = 32; o; o >>= 1) v += __shfl_xor(v, o, 64);
    return v;
}
__device__ inline float wredmax(float v) {
#pragma unroll
    for (int o = 32; o; o >>= 1) v = fmaxf(v, __shfl_xor(v, o, 64));
    return v;
}

// ---------------------------------------------------------------------------
// K1: degree + CSR neighbor lists from adj (values are exactly 0.0/1.0)
// ---------------------------------------------------------------------------
__global__ __launch_bounds__(256) void k_deg_nbr(const float* __restrict__ adj,
        unsigned short* __restrict__ nbr, int* __restrict__ nbr_cnt,
        float* __restrict__ dinv_gcn, float* __restrict__ dinv_info) {
    int wave = threadIdx.x >> 6, lane = threadIdx.x & 63;
    long long row = (long long)blockIdx.x * 4 + wave;   // < G*N1
    const float* arow = adj + row * N1;
    unsigned short* nrow = nbr + row * MAXD;
    int base = 0;
#pragma unroll
    for (int c = 0; c < N1 / 64; ++c) {
        float v = arow[c * 64 + lane];
        unsigned long long m = __ballot(v != 0.0f);
        if (v != 0.0f) {
            int off = __popcll(m & ((1ull << lane) - 1ull));
            int pos = base + off;
            if (pos < MAXD) nrow[pos] = (unsigned short)(c * 64 + lane);
        }
        base += __popcll(m);
    }
    if (lane == 0) {
        nbr_cnt[row] = base < MAXD ? base : MAXD;
        float deg = (float)base;
        dinv_gcn[row]  = rsqrtf(deg + 1.0f);
        dinv_info[row] = 1.0f / fmaxf(deg, 1.0f);
    }
}

// ---------------------------------------------------------------------------
// Row-weight GEMM: C[M,128] = A[M,128] @ W[128,128], fp32, 64-row tiles
// ---------------------------------------------------------------------------
__global__ __launch_bounds__(256) void k_gemm_rw(const float* __restrict__ A,
        const float* __restrict__ W, float* __restrict__ C) {
    __shared__ float Al[64][68];
    __shared__ float Wl[64][132];
    long long row0 = (long long)blockIdx.x * 64;
    int tid = threadIdx.x, tr = tid >> 4, tc = tid & 15;
    float acc[4][8] = {};
    for (int ch = 0; ch < 2; ++ch) {
        for (int p = tid; p < 1024; p += 256) {
            int r = p >> 4, c4 = p & 15;
            *(float4*)&Al[r][c4 * 4] = *(const float4*)(A + (row0 + r) * 128 + ch * 64 + c4 * 4);
        }
        for (int p = tid; p < 2048; p += 256) {
            int r = p >> 5, c4 = p & 31;
            *(float4*)&Wl[r][c4 * 4] = *(const float4*)(W + (ch * 64 + r) * 128 + c4 * 4);
        }
        __syncthreads();
        for (int k = 0; k < 64; ++k) {
            float4 w0 = *(const float4*)&Wl[k][tc * 8];
            float4 w1 = *(const float4*)&Wl[k][tc * 8 + 4];
            float w[8] = {w0.x, w0.y, w0.z, w0.w, w1.x, w1.y, w1.z, w1.w};
#pragma unroll
            for (int i = 0; i < 4; ++i) {
                float a = Al[tr * 4 + i][k];
#pragma unroll
                for (int j = 0; j < 8; ++j) acc[i][j] = fmaf(a, w[j], acc[i][j]);
            }
        }
        __syncthreads();
    }
#pragma unroll
    for (int i = 0; i < 4; ++i) {
        long long r = row0 + tr * 4 + i;
        *(float4*)(C + r * 128 + tc * 8)     = make_float4(acc[i][0], acc[i][1], acc[i][2], acc[i][3]);
        *(float4*)(C + r * 128 + tc * 8 + 4) = make_float4(acc[i][4], acc[i][5], acc[i][6], acc[i][7]);
    }
}

// ---------------------------------------------------------------------------
// gcn1 sparse aggregation + epilogue: h = relu(di*sum_j(dj*xw_j) + di^2*xw_i + b)
// ---------------------------------------------------------------------------
__global__ __launch_bounds__(256) void k_gcn1(const float* __restrict__ xw,
        const unsigned short* __restrict__ nbr, const int* __restrict__ nbr_cnt,
        const float* __restrict__ dinv, const float* __restrict__ b1,
        float* __restrict__ h1) {
    int wave = threadIdx.x >> 6, lane = threadIdx.x & 63;
    int row = blockIdx.x * 4 + wave;
    int g = row >> 9;
    const unsigned short* nrow = nbr + (long long)row * MAXD;
    int cnt = nbr_cnt[row];
    const float* xwg = xw + (long long)g * N1 * 128;
    const float* dg  = dinv + g * N1;
    float ax = 0.f, ay = 0.f;
    for (int t = 0; t < cnt; ++t) {
        int j = nrow[t];
        float dj = dg[j];
        float2 v = *(const float2*)(xwg + j * 128 + lane * 2);
        ax = fmaf(dj, v.x, ax); ay = fmaf(dj, v.y, ay);
    }
    float di = dinv[row], dd = di * di;
    float2 xv = *(const float2*)(xw + (long long)row * 128 + lane * 2);
    float2 bb = *(const float2*)(b1 + lane * 2);
    float2 o;
    o.x = fmaxf(fmaf(di, ax, fmaf(dd, xv.x, bb.x)), 0.f);
    o.y = fmaxf(fmaf(di, ay, fmaf(dd, xv.y, bb.y)), 0.f);
    *(float2*)(h1 + (long long)row * 128 + lane * 2) = o;
}

// ---------------------------------------------------------------------------
// info_score (sparse): s_i = sum_f |h_if - (sum_j h_jf)/max(deg,1)|
// ---------------------------------------------------------------------------
__global__ __launch_bounds__(256) void k_info1(const float* __restrict__ h,
        const unsigned short* __restrict__ nbr, const int* __restrict__ nbr_cnt,
        const float* __restrict__ dinfo, float* __restrict__ s) {
    int wave = threadIdx.x >> 6, lane = threadIdx.x & 63;
    int row = blockIdx.x * 4 + wave;
    int g = row >> 9;
    const unsigned short* nrow = nbr + (long long)row * MAXD;
    int cnt = nbr_cnt[row];
    const float* hg = h + (long long)g * N1 * 128;
    float ax = 0.f, ay = 0.f;
    for (int t = 0; t < cnt; ++t) {
        int j = nrow[t];
        float2 v = *(const float2*)(hg + j * 128 + lane * 2);
        ax += v.x; ay += v.y;
    }
    float di = dinfo[row];
    float2 hv = *(const float2*)(h + (long long)row * 128 + lane * 2);
    float p = fabsf(hv.x - ax * di) + fabsf(hv.y - ay * di);
    p = wredsum(p);
    if (lane == 0) s[row] = p;
}

// ---------------------------------------------------------------------------
// top-k: bitonic sort of packed keys (~ord(val) << 32 | idx) ascending
//  => value descending, index ascending tiebreak (matches jax.lax.top_k)
// ---------------------------------------------------------------------------
template<int NT, int KSEL>
__global__ __launch_bounds__(256) void k_topk(const float* __restrict__ s, int* __restrict__ idx) {
    __shared__ unsigned long long keys[NT];
    int g = blockIdx.x;
    const float* sg = s + g * NT;
    for (int t = threadIdx.x; t < NT; t += 256) {
        unsigned int b = __float_as_uint(sg[t]);
        unsigned int ord = (b & 0x80000000u) ? ~b : (b | 0x80000000u);
        keys[t] = ((unsigned long long)(~ord) << 32) | (unsigned int)t;
    }
    __syncthreads();
    for (int k = 2; k <= NT; k <<= 1) {
        for (int j = k >> 1; j > 0; j >>= 1) {
            for (int i = threadIdx.x; i < NT; i += 256) {
                int l = i ^ j;
                if (l > i) {
                    bool dir = ((i & k) == 0);
                    unsigned long long a = keys[i], b = keys[l];
                    bool sw = dir ? (a > b) : (a < b);
                    if (sw) { keys[i] = b; keys[l] = a; }
                }
            }
            __syncthreads();
        }
    }
    for (int t = threadIdx.x; t < KSEL; t += 256)
        idx[g * KSEL + t] = (int)(keys[t] & 0xffffffffu);
}

// ---------------------------------------------------------------------------
// gather pooled rows + attention dot products
// ---------------------------------------------------------------------------
template<int KK>
__global__ __launch_bounds__(256) void k_gather(const float* __restrict__ h, int srcN,
        const int* __restrict__ idx, const float* __restrict__ atts, const float* __restrict__ attd,
        float* __restrict__ xk, float* __restrict__ as_, float* __restrict__ ad_) {
    int wave = threadIdx.x >> 6, lane = threadIdx.x & 63;
    int r = blockIdx.x * 4 + wave;          // < G*KK
    int g = r / KK;
    int j = idx[r];
    float2 v = *(const float2*)(h + ((long long)g * srcN + j) * 128 + lane * 2);
    *(float2*)(xk + (long long)r * 128 + lane * 2) = v;
    float2 sv = *(const float2*)(atts + lane * 2);
    float2 dv = *(const float2*)(attd + lane * 2);
    float ps = v.x * sv.x + v.y * sv.y;
    float pd = v.x * dv.x + v.y * dv.y;
    ps = wredsum(ps); pd = wredsum(pd);
    if (lane == 0) { as_[r] = ps; ad_[r] = pd; }
}

// ---------------------------------------------------------------------------
// attention: attn = softmax(leaky(as_i + ad_j) + adjSrc[idx_i,idx_j]) + deg epilogue
// ---------------------------------------------------------------------------
template<int KK, int SRCN>
__global__ __launch_bounds__(256) void k_attn(const float* __restrict__ adjSrc,
        const int* __restrict__ idx, const float* __restrict__ as_, const float* __restrict__ ad_,
        float* __restrict__ attn, float* __restrict__ dgo, float* __restrict__ dio) {
    constexpr int E = KK / 64;
    __shared__ int   idxL[KK];
    __shared__ float adL[KK];
    __shared__ float rowL[4][SRCN];
    int bpg = KK / 4;
    int g = blockIdx.x / bpg;
    int wave = threadIdx.x >> 6, lane = threadIdx.x & 63;
    int i = (blockIdx.x % bpg) * 4 + wave;
    for (int t = threadIdx.x; t < KK; t += 256) { idxL[t] = idx[g * KK + t]; adL[t] = ad_[g * KK + t]; }
    __syncthreads();
    int ri = idxL[i];
    const float* arow = adjSrc + ((long long)g * SRCN + ri) * SRCN;
    for (int c = lane; c < SRCN; c += 64) rowL[wave][c] = arow[c];
    float asi = as_[g * KK + i];
    float vals[E];
    float m = -1e30f;
#pragma unroll
    for (int e = 0; e < E; ++e) {
        int j = e * 64 + lane;
        float x = asi + adL[j];
        x = (x >= 0.f) ? x : 0.2f * x;
        x += rowL[wave][idxL[j]];       // LAMB = 1.0
        vals[e] = x; m = fmaxf(m, x);
    }
    m = wredmax(m);
    float S = 0.f;
#pragma unroll
    for (int e = 0; e < E; ++e) { vals[e] = expf(vals[e] - m); S += vals[e]; }
    S = wredsum(S);
    float inv = 1.f / S, rs = 0.f;
    float* orow = attn + ((long long)g * KK + i) * KK;
#pragma unroll
    for (int e = 0; e < E; ++e) { float p = vals[e] * inv; rs += p; orow[e * 64 + lane] = p; }
    rs = wredsum(rs);
    if (lane == 0) { dgo[g * KK + i] = rsqrtf(rs + 1.f); dio[g * KK + i] = 1.f / fmaxf(rs, 1.f); }
}

// ---------------------------------------------------------------------------
// readout: [max over rows, mean over rows] -> (G, 256)
// ---------------------------------------------------------------------------
template<int KK>
__global__ __launch_bounds__(128) void k_readout(const float* __restrict__ xk, float* __restrict__ xo) {
    int g = blockIdx.x, f = threadIdx.x;
    const float* p = xk + (long long)g * KK * 128 + f;
    float m = -1e30f, s = 0.f;
    for (int r = 0; r < KK; ++r) { float v = p[r * 128]; m = fmaxf(m, v); s += v; }
    xo[g * 256 + f] = m;
    xo[g * 256 + 128 + f] = s * (1.0f / KK);
}

// ---------------------------------------------------------------------------
// dense batched agg GEMM: C = A(KKxKK) @ [opt dinv_j *] Y(KKx128)
//  EPI 0: outH = relu(di*C + di^2*hx + bias)   EPI 1: outS_i = sum_f |hx - C*di|
// ---------------------------------------------------------------------------
template<int KK, bool SCALEY, int EPI>
__global__ __launch_bounds__(256) void k_agg(const float* __restrict__ A, const float* __restrict__ Y,
        const float* __restrict__ dg, const float* __restrict__ di_,
        const float* __restrict__ bias, const float* __restrict__ hx,
        float* __restrict__ outH, float* __restrict__ outS) {
    __shared__ float Al[64][68];
    __shared__ float Yl[64][132];
    __shared__ float red[64][17];
    constexpr int RB = KK / 64;
    int g = blockIdx.x / RB;
    int rb = blockIdx.x % RB;
    const float* Ag = A + (long long)g * KK * KK;
    const float* Yg = Y + (long long)g * KK * 128;
    int tid = threadIdx.x, tr = tid >> 4, tc = tid & 15;
    float acc[4][8] = {};
    for (int ch = 0; ch < KK / 64; ++ch) {
        for (int p = tid; p < 1024; p += 256) {
            int r = p >> 4, c4 = p & 15;
            *(float4*)&Al[r][c4 * 4] = *(const float4*)(Ag + (rb * 64 + r) * KK + ch * 64 + c4 * 4);
        }
        for (int p = tid; p < 2048; p += 256) {
            int r = p >> 5, c4 = p & 31;
            float4 v = *(const float4*)(Yg + (ch * 64 + r) * 128 + c4 * 4);
            if (SCALEY) { float sc = dg[g * KK + ch * 64 + r]; v.x *= sc; v.y *= sc; v.z *= sc; v.w *= sc; }
            *(float4*)&Yl[r][c4 * 4] = v;
        }
        __syncthreads();
        for (int k = 0; k < 64; ++k) {
            float4 w0 = *(const float4*)&Yl[k][tc * 8];
            float4 w1 = *(const float4*)&Yl[k][tc * 8 + 4];
            float w[8] = {w0.x, w0.y, w0.z, w0.w, w1.x, w1.y, w1.z, w1.w};
#pragma unroll
            for (int i = 0; i < 4; ++i) {
                float a = Al[tr * 4 + i][k];
#pragma unroll
                for (int j = 0; j < 8; ++j) acc[i][j] = fmaf(a, w[j], acc[i][j]);
            }
        }
        __syncthreads();
    }
    int i0 = rb * 64 + tr * 4;
    if (EPI == 0) {
#pragma unroll
        for (int i = 0; i < 4; ++i) {
            long long gi = (long long)g * KK + i0 + i;
            float d = dg[gi], dd = d * d;
            float4 x0 = *(const float4*)(hx + gi * 128 + tc * 8);
            float4 x1 = *(const float4*)(hx + gi * 128 + tc * 8 + 4);
            float4 b0 = *(const float4*)(bias + tc * 8);
            float4 b1 = *(const float4*)(bias + tc * 8 + 4);
            float4 o0, o1;
            o0.x = fmaxf(fmaf(d, acc[i][0], fmaf(dd, x0.x, b0.x)), 0.f);
            o0.y = fmaxf(fmaf(d, acc[i][1], fmaf(dd, x0.y, b0.y)), 0.f);
            o0.z = fmaxf(fmaf(d, acc[i][2], fmaf(dd, x0.z, b0.z)), 0.f);
            o0.w = fmaxf(fmaf(d, acc[i][3], fmaf(dd, x0.w, b0.w)), 0.f);
            o1.x = fmaxf(fmaf(d, acc[i][4], fmaf(dd, x1.x, b1.x)), 0.f);
            o1.y = fmaxf(fmaf(d, acc[i][5], fmaf(dd, x1.y, b1.y)), 0.f);
            o1.z = fmaxf(fmaf(d, acc[i][6], fmaf(dd, x1.z, b1.z)), 0.f);
            o1.w = fmaxf(fmaf(d, acc[i][7], fmaf(dd, x1.w, b1.w)), 0.f);
            *(float4*)(outH + gi * 128 + tc * 8)     = o0;
            *(float4*)(outH + gi * 128 + tc * 8 + 4) = o1;
        }
    } else {
#pragma unroll
        for (int i = 0; i < 4; ++i) {
            long long gi = (long long)g * KK + i0 + i;
            float d = di_[gi];
            float4 x0 = *(const float4*)(hx + gi * 128 + tc * 8);
            float4 x1 = *(const float4*)(hx + gi * 128 + tc * 8 + 4);
            float p = fabsf(x0.x - acc[i][0] * d) + fabsf(x0.y - acc[i][1] * d)
                    + fabsf(x0.z - acc[i][2] * d) + fabsf(x0.w - acc[i][3] * d)
                    + fabsf(x1.x - acc[i][4] * d) + fabsf(x1.y - acc[i][5] * d)
                    + fabsf(x1.z - acc[i][6] * d) + fabsf(x1.w - acc[i][7] * d);
            red[tr * 4 + i][tc] = p;
        }
        __syncthreads();
        if (tid < 64) {
            float s = 0.f;
#pragma unroll
            for (int t = 0; t < 16; ++t) s += red[tid][t];
            outS[(long long)g * KK + rb * 64 + tid] = s;
        }
    }
}

// ---------------------------------------------------------------------------
// final MLP + softmax, one block per graph
// ---------------------------------------------------------------------------
__global__ __launch_bounds__(128) void k_mlp(const float* __restrict__ x1, const float* __restrict__ x2,
        const float* __restrict__ x3,
        const float* __restrict__ Wl1, const float* __restrict__ bl1,
        const float* __restrict__ Wl2, const float* __restrict__ bl2,
        const float* __restrict__ Wl3, const float* __restrict__ bl3,
        float* __restrict__ out) {
    __shared__ float z[256], z1[128], z2[64], lg[10];
    int g = blockIdx.x, t = threadIdx.x;
    for (int k = t; k < 256; k += 128)
        z[k] = fmaxf(x1[g * 256 + k], 0.f) + fmaxf(x2[g * 256 + k], 0.f) + fmaxf(x3[g * 256 + k], 0.f);
    __syncthreads();
    {
        float acc = bl1[t];
        for (int k = 0; k < 256; ++k) acc = fmaf(z[k], Wl1[k * 128 + t], acc);
        z1[t] = fmaxf(acc, 0.f);
    }
    __syncthreads();
    if (t < 64) {
        float acc = bl2[t];
        for (int k = 0; k < 128; ++k) acc = fmaf(z1[k], Wl2[k * 64 + t], acc);
        z2[t] = fmaxf(acc, 0.f);
    }
    __syncthreads();
    if (t < 10) {
        float acc = bl3[t];
        for (int k = 0; k < 64; ++k) acc = fmaf(z2[k], Wl3[k * 10 + t], acc);
        lg[t] = acc;
    }
    __syncthreads();
    if (t == 0) {
        float m = -1e30f;
        for (int c = 0; c < 10; ++c) m = fmaxf(m, lg[c]);
        float S = 0.f;
        float e[10];
        for (int c = 0; c < 10; ++c) { e[c] = expf(lg[c] - m); S += e[c]; }
        float inv = 1.f / S;
        for (int c = 0; c < 10; ++c) out[g * 10 + c] = e[c] * inv;
    }
}

// ---------------------------------------------------------------------------
extern "C" void kernel_launch(void* const* d_in, const int* in_sizes, int n_in,
                              void* d_out, int out_size, void* d_ws, size_t ws_size,
                              hipStream_t stream) {
    const float* x     = (const float*)d_in[0];
    const float* adj   = (const float*)d_in[1];
    const float* W1    = (const float*)d_in[2];
    const float* b1    = (const float*)d_in[3];
    const float* W2    = (const float*)d_in[4];
    const float* b2    = (const float*)d_in[5];
    const float* W3    = (const float*)d_in[6];
    const float* b3    = (const float*)d_in[7];
    const float* att1s = (const float*)d_in[8];
    const float* att1d = (const float*)d_in[9];
    const float* att2s = (const float*)d_in[10];
    const float* att2d = (const float*)d_in[11];
    const float* Wl1   = (const float*)d_in[12];
    const float* bl1   = (const float*)d_in[13];
    const float* Wl2   = (const float*)d_in[14];
    const float* bl2   = (const float*)d_in[15];
    const float* Wl3   = (const float*)d_in[16];
    const float* bl3   = (const float*)d_in[17];
    float* out = (float*)d_out;

    char* ws = (char*)d_ws;
    // workspace layout (102.4 MiB total); regions reused across stages
    unsigned short* nbr = (unsigned short*)(ws + 0);            // 20,971,520 B (later: xk2, a2)
    int*   nbr_cnt   = (int*)  (ws + 20971520);                 // 262,144
    float* dinv_g1   = (float*)(ws + 21233664);                 // 262,144
    float* dinv_i1   = (float*)(ws + 21495808);                 // 262,144
    float* R1        = (float*)(ws + 21757952);                 // 33,554,432: xw1 -> a1
    float* R2        = (float*)(ws + 55312384);                 // 33,554,432: h1 -> xw2|h2
    float* R3        = (float*)(ws + 88866816);                 // 16,777,216: xk1 -> xw3|h3
    float* s1        = (float*)(ws + 105644032);
    int*   idx1      = (int*)  (ws + 105906176);
    float* as1       = (float*)(ws + 106037248);
    float* ad1       = (float*)(ws + 106168320);
    float* dinv_g2   = (float*)(ws + 106299392);
    float* dinv_i2   = (float*)(ws + 106430464);
    float* x1r       = (float*)(ws + 106561536);
    float* s2        = (float*)(ws + 106692608);
    int*   idx2      = (int*)  (ws + 106823680);
    float* as2       = (float*)(ws + 106889216);
    float* ad2       = (float*)(ws + 106954752);
    float* dinv_g3   = (float*)(ws + 107020288);
    float* dinv_i3   = (float*)(ws + 107085824);
    float* x2r       = (float*)(ws + 107151360);
    float* x3r       = (float*)(ws + 107282432);

    float* xw1 = R1;                       // then a1 = R1
    float* a1  = R1;
    float* h1  = R2;
    float* xw2 = R2;                       // first half after h1 dead
    float* h2  = R2 + 16777216 / 4;
    float* xk1 = R3;
    float* xw3 = R3;                       // first half after xk1 dead
    float* h3  = R3 + 8388608 / 4;
    float* xk2 = (float*)(ws + 0);         // nbr region reuse
    float* a2  = (float*)(ws + 8388608);

    // stage 1: full graph (N=512)
    k_deg_nbr<<<Gg * N1 / 4, 256, 0, stream>>>(adj, nbr, nbr_cnt, dinv_g1, dinv_i1);
    k_gemm_rw<<<Gg * N1 / 64, 256, 0, stream>>>(x, W1, xw1);
    k_gcn1<<<Gg * N1 / 4, 256, 0, stream>>>(xw1, nbr, nbr_cnt, dinv_g1, b1, h1);
    k_info1<<<Gg * N1 / 4, 256, 0, stream>>>(h1, nbr, nbr_cnt, dinv_i1, s1);
    k_topk<N1, K1><<<Gg, 256, 0, stream>>>(s1, idx1);
    k_gather<K1><<<Gg * K1 / 4, 256, 0, stream>>>(h1, N1, idx1, att1s, att1d, xk1, as1, ad1);
    k_attn<K1, N1><<<Gg * K1 / 4, 256, 0, stream>>>(adj, idx1, as1, ad1, a1, dinv_g2, dinv_i2);
    k_readout<K1><<<Gg, 128, 0, stream>>>(xk1, x1r);

    // stage 2: pooled graph (K1=256), dense attention adjacency a1
    k_gemm_rw<<<Gg * K1 / 64, 256, 0, stream>>>(xk1, W2, xw2);
    k_agg<K1, true, 0><<<Gg * (K1 / 64), 256, 0, stream>>>(a1, xw2, dinv_g2, dinv_i2, b2, xw2, h2, nullptr);
    k_agg<K1, false, 1><<<Gg * (K1 / 64), 256, 0, stream>>>(a1, h2, dinv_g2, dinv_i2, b2, h2, nullptr, s2);
    k_topk<K1, K2><<<Gg, 256, 0, stream>>>(s2, idx2);
    k_gather<K2><<<Gg * K2 / 4, 256, 0, stream>>>(h2, K1, idx2, att2s, att2d, xk2, as2, ad2);
    k_attn<K2, K1><<<Gg * K2 / 4, 256, 0, stream>>>(a1, idx2, as2, ad2, a2, dinv_g3, dinv_i3);
    k_readout<K2><<<Gg, 128, 0, stream>>>(xk2, x2r);

    // stage 3: pooled graph (K2=128), dense attention adjacency a2
    k_gemm_rw<<<Gg * K2 / 64, 256, 0, stream>>>(xk2, W3, xw3);
    k_agg<K2, true, 0><<<Gg * (K2 / 64), 256, 0, stream>>>(a2, xw3, dinv_g3, dinv_i3, b3, xw3, h3, nullptr);
    k_readout<K2><<<Gg, 128, 0, stream>>>(h3, x3r);

    // final MLP
    k_mlp<<<Gg, 128, 0, stream>>>(x1r, x2r, x3r, Wl1, bl1, Wl2, bl2, Wl3, bl3, out);
}

// Round 2
// 812.978 us; speedup vs baseline: 1.3276x; 1.3276x over previous
//
#include <hip/hip_runtime.h>

// Sizes
#define Gg   128
#define N1   512
#define FH   128
#define K1   256
#define K2   128
#define MAXD 160

__device__ inline float wredsum(float v) {
#pragma unroll
    for (int o = 32; o; o >>= 1) v += __shfl_xor(v, o, 64);
    return v;
}
__device__ inline float wredmax(float v) {
#pragma unroll
    for (int o = 32; o; o >>= 1) v = fmaxf(v, __shfl_xor(v, o, 64));
    return v;
}

// XCD-aware swizzle: 16384 blocks, 128 blocks/graph, all blocks of graph g on
// XCD g%8 (round-robin dispatch: blockIdx%8 selects XCD). Returns row base.
__device__ inline int swz_row(int b) {
    int x8 = b & 7, i = b >> 3;           // i in [0,2048)
    int g  = x8 + ((i >> 7) << 3);        // 16 graphs per XCD
    return (g << 9) + ((i & 127) << 2);   // 4 rows per block
}

// ---------------------------------------------------------------------------
// K1: degree + CSR neighbor lists from adj (values are exactly 0.0/1.0)
// ---------------------------------------------------------------------------
__global__ __launch_bounds__(256) void k_deg_nbr(const float* __restrict__ adj,
        unsigned short* __restrict__ nbr, int* __restrict__ nbr_cnt,
        float* __restrict__ dinv_gcn, float* __restrict__ dinv_info) {
    int wave = threadIdx.x >> 6, lane = threadIdx.x & 63;
    long long row = (long long)blockIdx.x * 4 + wave;   // < G*N1
    const float* arow = adj + row * N1;
    unsigned short* nrow = nbr + row * MAXD;
    int base = 0;
#pragma unroll
    for (int c = 0; c < N1 / 64; ++c) {
        float v = arow[c * 64 + lane];
        unsigned long long m = __ballot(v != 0.0f);
        if (v != 0.0f) {
            int off = __popcll(m & ((1ull << lane) - 1ull));
            int pos = base + off;
            if (pos < MAXD) nrow[pos] = (unsigned short)(c * 64 + lane);
        }
        base += __popcll(m);
    }
    if (lane == 0) {
        nbr_cnt[row] = base < MAXD ? base : MAXD;
        float deg = (float)base;
        dinv_gcn[row]  = rsqrtf(deg + 1.0f);
        dinv_info[row] = 1.0f / fmaxf(deg, 1.0f);
    }
}

// ---------------------------------------------------------------------------
// Row-weight GEMM: C[M,128] = rs[row] * (A[M,128] @ W[128,128])  (rs optional)
// ---------------------------------------------------------------------------
__global__ __launch_bounds__(256) void k_gemm_rw(const float* __restrict__ A,
        const float* __restrict__ W, float* __restrict__ C,
        const float* __restrict__ rs) {
    __shared__ float Al[64][68];
    __shared__ float Wl[64][132];
    long long row0 = (long long)blockIdx.x * 64;
    int tid = threadIdx.x, tr = tid >> 4, tc = tid & 15;
    float acc[4][8] = {};
    for (int ch = 0; ch < 2; ++ch) {
        for (int p = tid; p < 1024; p += 256) {
            int r = p >> 4, c4 = p & 15;
            *(float4*)&Al[r][c4 * 4] = *(const float4*)(A + (row0 + r) * 128 + ch * 64 + c4 * 4);
        }
        for (int p = tid; p < 2048; p += 256) {
            int r = p >> 5, c4 = p & 31;
            *(float4*)&Wl[r][c4 * 4] = *(const float4*)(W + (ch * 64 + r) * 128 + c4 * 4);
        }
        __syncthreads();
        for (int k = 0; k < 64; ++k) {
            float4 w0 = *(const float4*)&Wl[k][tc * 8];
            float4 w1 = *(const float4*)&Wl[k][tc * 8 + 4];
            float w[8] = {w0.x, w0.y, w0.z, w0.w, w1.x, w1.y, w1.z, w1.w};
#pragma unroll
            for (int i = 0; i < 4; ++i) {
                float a = Al[tr * 4 + i][k];
#pragma unroll
                for (int j = 0; j < 8; ++j) acc[i][j] = fmaf(a, w[j], acc[i][j]);
            }
        }
        __syncthreads();
    }
#pragma unroll
    for (int i = 0; i < 4; ++i) {
        long long r = row0 + tr * 4 + i;
        float sc = rs ? rs[r] : 1.0f;
        *(float4*)(C + r * 128 + tc * 8)     = make_float4(sc * acc[i][0], sc * acc[i][1], sc * acc[i][2], sc * acc[i][3]);
        *(float4*)(C + r * 128 + tc * 8 + 4) = make_float4(sc * acc[i][4], sc * acc[i][5], sc * acc[i][6], sc * acc[i][7]);
    }
}

// ---------------------------------------------------------------------------
// gcn1 sparse aggregation on pre-scaled dxw (= dinv*xw):
//   h = relu(di * (sum_j dxw_j + dxw_i) + b)   [== di*agg + di^2*xw + b]
// ---------------------------------------------------------------------------
__global__ __launch_bounds__(256) void k_gcn1(const float* __restrict__ dxw,
        const unsigned short* __restrict__ nbr, const int* __restrict__ nbr_cnt,
        const float* __restrict__ dinv, const float* __restrict__ b1,
        float* __restrict__ h1) {
    int wave = threadIdx.x >> 6, lane = threadIdx.x & 63;
    int row = swz_row(blockIdx.x) + wave;
    int g = row >> 9;
    const unsigned short* nrow = nbr + (long long)row * MAXD;
    int cnt = nbr_cnt[row];
    const float* xwg = dxw + (long long)g * N1 * 128;
    float ax = 0.f, ay = 0.f;
    int t = 0;
    for (; t + 4 <= cnt; t += 4) {
        int j0 = nrow[t], j1 = nrow[t + 1], j2 = nrow[t + 2], j3 = nrow[t + 3];
        float2 v0 = *(const float2*)(xwg + j0 * 128 + lane * 2);
        float2 v1 = *(const float2*)(xwg + j1 * 128 + lane * 2);
        float2 v2 = *(const float2*)(xwg + j2 * 128 + lane * 2);
        float2 v3 = *(const float2*)(xwg + j3 * 128 + lane * 2);
        ax += (v0.x + v1.x) + (v2.x + v3.x);
        ay += (v0.y + v1.y) + (v2.y + v3.y);
    }
    for (; t < cnt; ++t) {
        int j = nrow[t];
        float2 v = *(const float2*)(xwg + j * 128 + lane * 2);
        ax += v.x; ay += v.y;
    }
    float di = dinv[row];
    float2 xv = *(const float2*)(dxw + (long long)row * 128 + lane * 2);
    float2 bb = *(const float2*)(b1 + lane * 2);
    float2 o;
    o.x = fmaxf(fmaf(di, ax + xv.x, bb.x), 0.f);
    o.y = fmaxf(fmaf(di, ay + xv.y, bb.y), 0.f);
    *(float2*)(h1 + (long long)row * 128 + lane * 2) = o;
}

// ---------------------------------------------------------------------------
// info_score (sparse): s_i = sum_f |h_if - (sum_j h_jf)/max(deg,1)|
// ---------------------------------------------------------------------------
__global__ __launch_bounds__(256) void k_info1(const float* __restrict__ h,
        const unsigned short* __restrict__ nbr, const int* __restrict__ nbr_cnt,
        const float* __restrict__ dinfo, float* __restrict__ s) {
    int wave = threadIdx.x >> 6, lane = threadIdx.x & 63;
    int row = swz_row(blockIdx.x) + wave;
    int g = row >> 9;
    const unsigned short* nrow = nbr + (long long)row * MAXD;
    int cnt = nbr_cnt[row];
    const float* hg = h + (long long)g * N1 * 128;
    float ax = 0.f, ay = 0.f;
    int t = 0;
    for (; t + 4 <= cnt; t += 4) {
        int j0 = nrow[t], j1 = nrow[t + 1], j2 = nrow[t + 2], j3 = nrow[t + 3];
        float2 v0 = *(const float2*)(hg + j0 * 128 + lane * 2);
        float2 v1 = *(const float2*)(hg + j1 * 128 + lane * 2);
        float2 v2 = *(const float2*)(hg + j2 * 128 + lane * 2);
        float2 v3 = *(const float2*)(hg + j3 * 128 + lane * 2);
        ax += (v0.x + v1.x) + (v2.x + v3.x);
        ay += (v0.y + v1.y) + (v2.y + v3.y);
    }
    for (; t < cnt; ++t) {
        int j = nrow[t];
        float2 v = *(const float2*)(hg + j * 128 + lane * 2);
        ax += v.x; ay += v.y;
    }
    float di = dinfo[row];
    float2 hv = *(const float2*)(h + (long long)row * 128 + lane * 2);
    float p = fabsf(hv.x - ax * di) + fabsf(hv.y - ay * di);
    p = wredsum(p);
    if (lane == 0) s[row] = p;
}

// ---------------------------------------------------------------------------
// top-k: bitonic sort of packed keys (~ord(val) << 32 | idx) ascending
//  => value descending, index ascending tiebreak (matches jax.lax.top_k)
// ---------------------------------------------------------------------------
template<int NT, int KSEL>
__global__ __launch_bounds__(256) void k_topk(const float* __restrict__ s, int* __restrict__ idx) {
    __shared__ unsigned long long keys[NT];
    int g = blockIdx.x;
    const float* sg = s + g * NT;
    for (int t = threadIdx.x; t < NT; t += 256) {
        unsigned int b = __float_as_uint(sg[t]);
        unsigned int ord = (b & 0x80000000u) ? ~b : (b | 0x80000000u);
        keys[t] = ((unsigned long long)(~ord) << 32) | (unsigned int)t;
    }
    __syncthreads();
    for (int k = 2; k <= NT; k <<= 1) {
        for (int j = k >> 1; j > 0; j >>= 1) {
            for (int i = threadIdx.x; i < NT; i += 256) {
                int l = i ^ j;
                if (l > i) {
                    bool dir = ((i & k) == 0);
                    unsigned long long a = keys[i], b = keys[l];
                    bool sw = dir ? (a > b) : (a < b);
                    if (sw) { keys[i] = b; keys[l] = a; }
                }
            }
            __syncthreads();
        }
    }
    for (int t = threadIdx.x; t < KSEL; t += 256)
        idx[g * KSEL + t] = (int)(keys[t] & 0xffffffffu);
}

// ---------------------------------------------------------------------------
// gather pooled rows + attention dot products
// ---------------------------------------------------------------------------
template<int KK>
__global__ __launch_bounds__(256) void k_gather(const float* __restrict__ h, int srcN,
        const int* __restrict__ idx, const float* __restrict__ atts, const float* __restrict__ attd,
        float* __restrict__ xk, float* __restrict__ as_, float* __restrict__ ad_) {
    int wave = threadIdx.x >> 6, lane = threadIdx.x & 63;
    int r = blockIdx.x * 4 + wave;          // < G*KK
    int g = r / KK;
    int j = idx[r];
    float2 v = *(const float2*)(h + ((long long)g * srcN + j) * 128 + lane * 2);
    *(float2*)(xk + (long long)r * 128 + lane * 2) = v;
    float2 sv = *(const float2*)(atts + lane * 2);
    float2 dv = *(const float2*)(attd + lane * 2);
    float ps = v.x * sv.x + v.y * sv.y;
    float pd = v.x * dv.x + v.y * dv.y;
    ps = wredsum(ps); pd = wredsum(pd);
    if (lane == 0) { as_[r] = ps; ad_[r] = pd; }
}

// ---------------------------------------------------------------------------
// attention: attn = softmax(leaky(as_i + ad_j) + adjSrc[idx_i,idx_j]) + deg epilogue
// ---------------------------------------------------------------------------
template<int KK, int SRCN>
__global__ __launch_bounds__(256) void k_attn(const float* __restrict__ adjSrc,
        const int* __restrict__ idx, const float* __restrict__ as_, const float* __restrict__ ad_,
        float* __restrict__ attn, float* __restrict__ dgo, float* __restrict__ dio) {
    constexpr int E = KK / 64;
    __shared__ int   idxL[KK];
    __shared__ float adL[KK];
    __shared__ float rowL[4][SRCN];
    int bpg = KK / 4;
    int g = blockIdx.x / bpg;
    int wave = threadIdx.x >> 6, lane = threadIdx.x & 63;
    int i = (blockIdx.x % bpg) * 4 + wave;
    for (int t = threadIdx.x; t < KK; t += 256) { idxL[t] = idx[g * KK + t]; adL[t] = ad_[g * KK + t]; }
    __syncthreads();
    int ri = idxL[i];
    const float* arow = adjSrc + ((long long)g * SRCN + ri) * SRCN;
    for (int c = lane; c < SRCN; c += 64) rowL[wave][c] = arow[c];
    float asi = as_[g * KK + i];
    float vals[E];
    float m = -1e30f;
#pragma unroll
    for (int e = 0; e < E; ++e) {
        int j = e * 64 + lane;
        float x = asi + adL[j];
        x = (x >= 0.f) ? x : 0.2f * x;
        x += rowL[wave][idxL[j]];       // LAMB = 1.0
        vals[e] = x; m = fmaxf(m, x);
    }
    m = wredmax(m);
    float S = 0.f;
#pragma unroll
    for (int e = 0; e < E; ++e) { vals[e] = expf(vals[e] - m); S += vals[e]; }
    S = wredsum(S);
    float inv = 1.f / S, rs = 0.f;
    float* orow = attn + ((long long)g * KK + i) * KK;
#pragma unroll
    for (int e = 0; e < E; ++e) { float p = vals[e] * inv; rs += p; orow[e * 64 + lane] = p; }
    rs = wredsum(rs);
    if (lane == 0) { dgo[g * KK + i] = rsqrtf(rs + 1.f); dio[g * KK + i] = 1.f / fmaxf(rs, 1.f); }
}

// ---------------------------------------------------------------------------
// readout: [max over rows, mean over rows] -> (G, 256)
// ---------------------------------------------------------------------------
template<int KK>
__global__ __launch_bounds__(128) void k_readout(const float* __restrict__ xk, float* __restrict__ xo) {
    int g = blockIdx.x, f = threadIdx.x;
    const float* p = xk + (long long)g * KK * 128 + f;
    float m = -1e30f, s = 0.f;
    for (int r = 0; r < KK; ++r) { float v = p[r * 128]; m = fmaxf(m, v); s += v; }
    xo[g * 256 + f] = m;
    xo[g * 256 + 128 + f] = s * (1.0f / KK);
}

// ---------------------------------------------------------------------------
// dense batched agg GEMM: C = A(KKxKK) @ [opt dinv_j *] Y(KKx128)
//  EPI 0: outH = relu(di*C + di^2*hx + bias)   EPI 1: outS_i = sum_f |hx - C*di|
// ---------------------------------------------------------------------------
template<int KK, bool SCALEY, int EPI>
__global__ __launch_bounds__(256) void k_agg(const float* __restrict__ A, const float* __restrict__ Y,
        const float* __restrict__ dg, const float* __restrict__ di_,
        const float* __restrict__ bias, const float* __restrict__ hx,
        float* __restrict__ outH, float* __restrict__ outS) {
    __shared__ float Al[64][68];
    __shared__ float Yl[64][132];
    __shared__ float red[64][17];
    constexpr int RB = KK / 64;
    int g = blockIdx.x / RB;
    int rb = blockIdx.x % RB;
    const float* Ag = A + (long long)g * KK * KK;
    const float* Yg = Y + (long long)g * KK * 128;
    int tid = threadIdx.x, tr = tid >> 4, tc = tid & 15;
    float acc[4][8] = {};
    for (int ch = 0; ch < KK / 64; ++ch) {
        for (int p = tid; p < 1024; p += 256) {
            int r = p >> 4, c4 = p & 15;
            *(float4*)&Al[r][c4 * 4] = *(const float4*)(Ag + (rb * 64 + r) * KK + ch * 64 + c4 * 4);
        }
        for (int p = tid; p < 2048; p += 256) {
            int r = p >> 5, c4 = p & 31;
            float4 v = *(const float4*)(Yg + (ch * 64 + r) * 128 + c4 * 4);
            if (SCALEY) { float sc = dg[g * KK + ch * 64 + r]; v.x *= sc; v.y *= sc; v.z *= sc; v.w *= sc; }
            *(float4*)&Yl[r][c4 * 4] = v;
        }
        __syncthreads();
        for (int k = 0; k < 64; ++k) {
            float4 w0 = *(const float4*)&Yl[k][tc * 8];
            float4 w1 = *(const float4*)&Yl[k][tc * 8 + 4];
            float w[8] = {w0.x, w0.y, w0.z, w0.w, w1.x, w1.y, w1.z, w1.w};
#pragma unroll
            for (int i = 0; i < 4; ++i) {
                float a = Al[tr * 4 + i][k];
#pragma unroll
                for (int j = 0; j < 8; ++j) acc[i][j] = fmaf(a, w[j], acc[i][j]);
            }
        }
        __syncthreads();
    }
    int i0 = rb * 64 + tr * 4;
    if (EPI == 0) {
#pragma unroll
        for (int i = 0; i < 4; ++i) {
            long long gi = (long long)g * KK + i0 + i;
            float d = dg[gi], dd = d * d;
            float4 x0 = *(const float4*)(hx + gi * 128 + tc * 8);
            float4 x1 = *(const float4*)(hx + gi * 128 + tc * 8 + 4);
            float4 b0 = *(const float4*)(bias + tc * 8);
            float4 b1 = *(const float4*)(bias + tc * 8 + 4);
            float4 o0, o1;
            o0.x = fmaxf(fmaf(d, acc[i][0], fmaf(dd, x0.x, b0.x)), 0.f);
            o0.y = fmaxf(fmaf(d, acc[i][1], fmaf(dd, x0.y, b0.y)), 0.f);
            o0.z = fmaxf(fmaf(d, acc[i][2], fmaf(dd, x0.z, b0.z)), 0.f);
            o0.w = fmaxf(fmaf(d, acc[i][3], fmaf(dd, x0.w, b0.w)), 0.f);
            o1.x = fmaxf(fmaf(d, acc[i][4], fmaf(dd, x1.x, b1.x)), 0.f);
            o1.y = fmaxf(fmaf(d, acc[i][5], fmaf(dd, x1.y, b1.y)), 0.f);
            o1.z = fmaxf(fmaf(d, acc[i][6], fmaf(dd, x1.z, b1.z)), 0.f);
            o1.w = fmaxf(fmaf(d, acc[i][7], fmaf(dd, x1.w, b1.w)), 0.f);
            *(float4*)(outH + gi * 128 + tc * 8)     = o0;
            *(float4*)(outH + gi * 128 + tc * 8 + 4) = o1;
        }
    } else {
#pragma unroll
        for (int i = 0; i < 4; ++i) {
            long long gi = (long long)g * KK + i0 + i;
            float d = di_[gi];
            float4 x0 = *(const float4*)(hx + gi * 128 + tc * 8);
            float4 x1 = *(const float4*)(hx + gi * 128 + tc * 8 + 4);
            float p = fabsf(x0.x - acc[i][0] * d) + fabsf(x0.y - acc[i][1] * d)
                    + fabsf(x0.z - acc[i][2] * d) + fabsf(x0.w - acc[i][3] * d)
                    + fabsf(x1.x - acc[i][4] * d) + fabsf(x1.y - acc[i][5] * d)
                    + fabsf(x1.z - acc[i][6] * d) + fabsf(x1.w - acc[i][7] * d);
            red[tr * 4 + i][tc] = p;
        }
        __syncthreads();
        if (tid < 64) {
            float s = 0.f;
#pragma unroll
            for (int t = 0; t < 16; ++t) s += red[tid][t];
            outS[(long long)g * KK + rb * 64 + tid] = s;
        }
    }
}

// ---------------------------------------------------------------------------
// final MLP + softmax, one block per graph
// ---------------------------------------------------------------------------
__global__ __launch_bounds__(128) void k_mlp(const float* __restrict__ x1, const float* __restrict__ x2,
        const float* __restrict__ x3,
        const float* __restrict__ Wl1, const float* __restrict__ bl1,
        const float* __restrict__ Wl2, const float* __restrict__ bl2,
        const float* __restrict__ Wl3, const float* __restrict__ bl3,
        float* __restrict__ out) {
    __shared__ float z[256], z1[128], z2[64], lg[10];
    int g = blockIdx.x, t = threadIdx.x;
    for (int k = t; k < 256; k += 128)
        z[k] = fmaxf(x1[g * 256 + k], 0.f) + fmaxf(x2[g * 256 + k], 0.f) + fmaxf(x3[g * 256 + k], 0.f);
    __syncthreads();
    {
        float acc = bl1[t];
        for (int k = 0; k < 256; ++k) acc = fmaf(z[k], Wl1[k * 128 + t], acc);
        z1[t] = fmaxf(acc, 0.f);
    }
    __syncthreads();
    if (t < 64) {
        float acc = bl2[t];
        for (int k = 0; k < 128; ++k) acc = fmaf(z1[k], Wl2[k * 64 + t], acc);
        z2[t] = fmaxf(acc, 0.f);
    }
    __syncthreads();
    if (t < 10) {
        float acc = bl3[t];
        for (int k = 0; k < 64; ++k) acc = fmaf(z2[k], Wl3[k * 10 + t], acc);
        lg[t] = acc;
    }
    __syncthreads();
    if (t == 0) {
        float m = -1e30f;
        for (int c = 0; c < 10; ++c) m = fmaxf(m, lg[c]);
        float S = 0.f;
        float e[10];
        for (int c = 0; c < 10; ++c) { e[c] = expf(lg[c] - m); S += e[c]; }
        float inv = 1.f / S;
        for (int c = 0; c < 10; ++c) out[g * 10 + c] = e[c] * inv;
    }
}

// ---------------------------------------------------------------------------
extern "C" void kernel_launch(void* const* d_in, const int* in_sizes, int n_in,
                              void* d_out, int out_size, void* d_ws, size_t ws_size,
                              hipStream_t stream) {
    const float* x     = (const float*)d_in[0];
    const float* adj   = (const float*)d_in[1];
    const float* W1    = (const float*)d_in[2];
    const float* b1    = (const float*)d_in[3];
    const float* W2    = (const float*)d_in[4];
    const float* b2    = (const float*)d_in[5];
    const float* W3    = (const float*)d_in[6];
    const float* b3    = (const float*)d_in[7];
    const float* att1s = (const float*)d_in[8];
    const float* att1d = (const float*)d_in[9];
    const float* att2s = (const float*)d_in[10];
    const float* att2d = (const float*)d_in[11];
    const float* Wl1   = (const float*)d_in[12];
    const float* bl1   = (const float*)d_in[13];
    const float* Wl2   = (const float*)d_in[14];
    const float* bl2   = (const float*)d_in[15];
    const float* Wl3   = (const float*)d_in[16];
    const float* bl3   = (const float*)d_in[17];
    float* out = (float*)d_out;

    char* ws = (char*)d_ws;
    // workspace layout (102.4 MiB total); regions reused across stages
    unsigned short* nbr = (unsigned short*)(ws + 0);            // 20,971,520 B (later: xk2, a2)
    int*   nbr_cnt   = (int*)  (ws + 20971520);                 // 262,144
    float* dinv_g1   = (float*)(ws + 21233664);                 // 262,144
    float* dinv_i1   = (float*)(ws + 21495808);                 // 262,144
    float* R1        = (float*)(ws + 21757952);                 // 33,554,432: dxw1 -> a1
    float* R2        = (float*)(ws + 55312384);                 // 33,554,432: h1 -> xw2|h2
    float* R3        = (float*)(ws + 88866816);                 // 16,777,216: xk1 -> xw3|h3
    float* s1        = (float*)(ws + 105644032);
    int*   idx1      = (int*)  (ws + 105906176);
    float* as1       = (float*)(ws + 106037248);
    float* ad1       = (float*)(ws + 106168320);
    float* dinv_g2   = (float*)(ws + 106299392);
    float* dinv_i2   = (float*)(ws + 106430464);
    float* x1r       = (float*)(ws + 106561536);
    float* s2        = (float*)(ws + 106692608);
    int*   idx2      = (int*)  (ws + 106823680);
    float* as2       = (float*)(ws + 106889216);
    float* ad2       = (float*)(ws + 106954752);
    float* dinv_g3   = (float*)(ws + 107020288);
    float* dinv_i3   = (float*)(ws + 107085824);
    float* x2r       = (float*)(ws + 107151360);
    float* x3r       = (float*)(ws + 107282432);

    float* dxw1 = R1;                      // pre-scaled xw1; then a1 = R1
    float* a1  = R1;
    float* h1  = R2;
    float* xw2 = R2;                       // first half after h1 dead
    float* h2  = R2 + 16777216 / 4;
    float* xk1 = R3;
    float* xw3 = R3;                       // first half after xk1 dead
    float* h3  = R3 + 8388608 / 4;
    float* xk2 = (float*)(ws + 0);         // nbr region reuse
    float* a2  = (float*)(ws + 8388608);

    // stage 1: full graph (N=512)
    k_deg_nbr<<<Gg * N1 / 4, 256, 0, stream>>>(adj, nbr, nbr_cnt, dinv_g1, dinv_i1);
    k_gemm_rw<<<Gg * N1 / 64, 256, 0, stream>>>(x, W1, dxw1, dinv_g1);
    k_gcn1<<<Gg * N1 / 4, 256, 0, stream>>>(dxw1, nbr, nbr_cnt, dinv_g1, b1, h1);
    k_info1<<<Gg * N1 / 4, 256, 0, stream>>>(h1, nbr, nbr_cnt, dinv_i1, s1);
    k_topk<N1, K1><<<Gg, 256, 0, stream>>>(s1, idx1);
    k_gather<K1><<<Gg * K1 / 4, 256, 0, stream>>>(h1, N1, idx1, att1s, att1d, xk1, as1, ad1);
    k_attn<K1, N1><<<Gg * K1 / 4, 256, 0, stream>>>(adj, idx1, as1, ad1, a1, dinv_g2, dinv_i2);
    k_readout<K1><<<Gg, 128, 0, stream>>>(xk1, x1r);

    // stage 2: pooled graph (K1=256), dense attention adjacency a1
    k_gemm_rw<<<Gg * K1 / 64, 256, 0, stream>>>(xk1, W2, xw2, nullptr);
    k_agg<K1, true, 0><<<Gg * (K1 / 64), 256, 0, stream>>>(a1, xw2, dinv_g2, dinv_i2, b2, xw2, h2, nullptr);
    k_agg<K1, false, 1><<<Gg * (K1 / 64), 256, 0, stream>>>(a1, h2, dinv_g2, dinv_i2, b2, h2, nullptr, s2);
    k_topk<K1, K2><<<Gg, 256, 0, stream>>>(s2, idx2);
    k_gather<K2><<<Gg * K2 / 4, 256, 0, stream>>>(h2, K1, idx2, att2s, att2d, xk2, as2, ad2);
    k_attn<K2, K1><<<Gg * K2 / 4, 256, 0, stream>>>(a1, idx2, as2, ad2, a2, dinv_g3, dinv_i3);
    k_readout<K2><<<Gg, 128, 0, stream>>>(xk2, x2r);

    // stage 3: pooled graph (K2=128), dense attention adjacency a2
    k_gemm_rw<<<Gg * K2 / 64, 256, 0, stream>>>(xk2, W3, xw3, nullptr);
    k_agg<K2, true, 0><<<Gg * (K2 / 64), 256, 0, stream>>>(a2, xw3, dinv_g3, dinv_i3, b3, xw3, h3, nullptr);
    k_readout<K2><<<Gg, 128, 0, stream>>>(h3, x3r);

    // final MLP
    k_mlp<<<Gg, 128, 0, stream>>>(x1r, x2r, x3r, Wl1, bl1, Wl2, bl2, Wl3, bl3, out);
}

// Round 3
// 606.793 us; speedup vs baseline: 1.7786x; 1.3398x over previous
//
#include <hip/hip_runtime.h>

// Sizes
#define Gg   128
#define N1   512
#define FH   128
#define K1   256
#define K2   128

typedef __bf16 bf16x8 __attribute__((ext_vector_type(8)));
typedef float  floatx4 __attribute__((ext_vector_type(4)));

__device__ inline float wredsum(float v) {
#pragma unroll
    for (int o = 32; o; o >>= 1) v += __shfl_xor(v, o, 64);
    return v;
}
__device__ inline float wredmax(float v) {
#pragma unroll
    for (int o = 32; o; o >>= 1) v = fmaxf(v, __shfl_xor(v, o, 64));
    return v;
}
__device__ inline unsigned short bf_rne(float x) {
    unsigned u = __float_as_uint(x);
    return (unsigned short)((u + 0x7fffu + ((u >> 16) & 1u)) >> 16);
}

// ---------------------------------------------------------------------------
// degrees from adj (row sums; adj values exactly 0/1)
// ---------------------------------------------------------------------------
__global__ __launch_bounds__(256) void k_prep(const float* __restrict__ adj,
        float* __restrict__ dinv_gcn, float* __restrict__ dinv_info) {
    int wave = threadIdx.x >> 6, lane = threadIdx.x & 63;
    long long row = (long long)blockIdx.x * 4 + wave;
    const float* ar = adj + row * N1;
    float s = 0.f;
#pragma unroll
    for (int c = 0; c < 2; ++c) {
        float4 v = *(const float4*)(ar + lane * 8 + c * 4);
        s += (v.x + v.y) + (v.z + v.w);
    }
    s = wredsum(s);
    if (lane == 0) {
        dinv_gcn[row]  = rsqrtf(s + 1.0f);
        dinv_info[row] = 1.0f / fmaxf(s, 1.0f);
    }
}

// ---------------------------------------------------------------------------
// transpose + 3-way bf16 split: feat[g*512][128] fp32 -> T{hi,mid,lo}[g][128][512]
// ---------------------------------------------------------------------------
__global__ __launch_bounds__(256) void k_tsplit(const float* __restrict__ feat,
        unsigned short* __restrict__ Thi, unsigned short* __restrict__ Tmid,
        unsigned short* __restrict__ Tlo) {
    __shared__ float tile[64 * 65];
    int b = blockIdx.x;                    // G * 8 * 2
    int g = b >> 4, rb = (b >> 1) & 7, cb = b & 1;
    int t = threadIdx.x;
    {
        int r0 = t >> 4, c4 = t & 15;
#pragma unroll
        for (int i = 0; i < 4; ++i) {
            int r = r0 + i * 16;
            float4 v = *(const float4*)(feat + ((long long)g * 512 + rb * 64 + r) * 128 + cb * 64 + c4 * 4);
            tile[r * 65 + c4 * 4 + 0] = v.x;
            tile[r * 65 + c4 * 4 + 1] = v.y;
            tile[r * 65 + c4 * 4 + 2] = v.z;
            tile[r * 65 + c4 * 4 + 3] = v.w;
        }
    }
    __syncthreads();
    int tf = t >> 2, chunk = t & 3;
    unsigned short hbuf[16] __attribute__((aligned(16)));
    unsigned short mbuf[16] __attribute__((aligned(16)));
    unsigned short lbuf[16] __attribute__((aligned(16)));
#pragma unroll
    for (int i = 0; i < 16; ++i) {
        int m = chunk * 16 + i;
        float v = tile[m * 65 + tf];
        unsigned short h = bf_rne(v);
        float fh = __uint_as_float((unsigned)h << 16);
        float r1 = v - fh;
        unsigned short md = bf_rne(r1);
        float fm = __uint_as_float((unsigned)md << 16);
        float r2 = r1 - fm;
        unsigned short lo = bf_rne(r2);
        hbuf[i] = h; mbuf[i] = md; lbuf[i] = lo;
    }
    long long obase = ((long long)g * 128 + cb * 64 + tf) * 512 + rb * 64 + chunk * 16;
    *(uint4*)(Thi + obase)      = *(const uint4*)&hbuf[0];
    *(uint4*)(Thi + obase + 8)  = *(const uint4*)&hbuf[8];
    *(uint4*)(Tmid + obase)     = *(const uint4*)&mbuf[0];
    *(uint4*)(Tmid + obase + 8) = *(const uint4*)&mbuf[8];
    *(uint4*)(Tlo + obase)      = *(const uint4*)&lbuf[0];
    *(uint4*)(Tlo + obase + 8)  = *(const uint4*)&lbuf[8];
}

// ---------------------------------------------------------------------------
// MFMA aggregation: C = adj(512x512, exact bf16) @ (Bhi+Bmid+Blo)(512x128)
//  EPI 0 (gcn):  outH[m][n] = relu(di[m]*(C+hx[m][n]) + bias[n])   (in-place over hx ok)
//  EPI 1 (info): outS[m]    = sum_n |hx[m][n] - C*di[m]|
// Block: 128 rows x 128 cols, 4 waves (2x2 of 64x64), mfma_f32_16x16x32_bf16.
// A converted fp32->bf16 on the fly (exact for 0/1). adj rows served from L3.
// ---------------------------------------------------------------------------
template<int EPI>
__global__ __launch_bounds__(256) void k_aggmm(const float* __restrict__ adjf,
        const unsigned short* __restrict__ Bhi, const unsigned short* __restrict__ Bmid,
        const unsigned short* __restrict__ Blo,
        const float* __restrict__ dvec, const float* __restrict__ hx,
        const float* __restrict__ bias, float* __restrict__ outH, float* __restrict__ outS) {
    __shared__ unsigned short Al[128 * 40];
    __shared__ unsigned short Bls[3][128 * 40];
    __shared__ float sred[2][128];
    int b = blockIdx.x;                               // 512 blocks
    int g  = (b & 7) + ((b >> 5) << 3);               // XCD swizzle: 4 row-blocks of g share an XCD
    int rb = (b >> 3) & 3;
    int tid = threadIdx.x;
    int w = tid >> 6, lane = tid & 63;
    int wm = w >> 1, wn = w & 1;
    int ln = lane & 15, quad = lane >> 4;
    floatx4 acc[4][4];
#pragma unroll
    for (int i = 0; i < 4; ++i)
#pragma unroll
        for (int j = 0; j < 4; ++j) { floatx4 z = {0.f, 0.f, 0.f, 0.f}; acc[i][j] = z; }

    const long long arow0 = ((long long)g * 512 + rb * 128) * 512;
    for (int kk = 0; kk < 512; kk += 32) {
        __syncthreads();
        // stage A (fp32 adj -> bf16, exact for 0/1 via truncation)
#pragma unroll
        for (int i = 0; i < 4; ++i) {
            int id = tid + i * 256;
            int r = id >> 3, c = id & 7;
            float4 v = *(const float4*)(adjf + arow0 + (long long)r * 512 + kk + c * 4);
            ushort4 u;
            u.x = (unsigned short)(__float_as_uint(v.x) >> 16);
            u.y = (unsigned short)(__float_as_uint(v.y) >> 16);
            u.z = (unsigned short)(__float_as_uint(v.z) >> 16);
            u.w = (unsigned short)(__float_as_uint(v.w) >> 16);
            *(ushort4*)&Al[r * 40 + c * 4] = u;
        }
        // stage B parts ([n][k] layout, k-contiguous)
#pragma unroll
        for (int mB = 0; mB < 3; ++mB) {
            const unsigned short* Bp = (mB == 0) ? Bhi : (mB == 1 ? Bmid : Blo);
#pragma unroll
            for (int i = 0; i < 2; ++i) {
                int id = tid + i * 256;
                int r = id >> 2, c = id & 3;
                uint4 u = *(const uint4*)(Bp + ((long long)g * 128 + r) * 512 + kk + c * 8);
                *(uint4*)&Bls[mB][r * 40 + c * 8] = u;
            }
        }
        __syncthreads();
        bf16x8 af[4];
#pragma unroll
        for (int tm = 0; tm < 4; ++tm)
            af[tm] = *(const bf16x8*)&Al[(wm * 64 + tm * 16 + ln) * 40 + quad * 8];
#pragma unroll
        for (int s = 0; s < 3; ++s) {
#pragma unroll
            for (int tn = 0; tn < 4; ++tn) {
                bf16x8 bfr = *(const bf16x8*)&Bls[s][(wn * 64 + tn * 16 + ln) * 40 + quad * 8];
#pragma unroll
                for (int tm = 0; tm < 4; ++tm)
                    acc[tm][tn] = __builtin_amdgcn_mfma_f32_16x16x32_bf16(af[tm], bfr, acc[tm][tn], 0, 0, 0);
            }
        }
    }
    long long rowbase = (long long)g * 512 + rb * 128;
    if (EPI == 0) {
#pragma unroll
        for (int tm = 0; tm < 4; ++tm)
#pragma unroll
        for (int r = 0; r < 4; ++r) {
            int ml = wm * 64 + tm * 16 + quad * 4 + r;
            long long grow = rowbase + ml;
            float di = dvec[grow];
#pragma unroll
            for (int tn = 0; tn < 4; ++tn) {
                int nc = wn * 64 + tn * 16 + ln;
                float hv = hx[grow * 128 + nc];
                float o = fmaxf(fmaf(di, acc[tm][tn][r] + hv, bias[nc]), 0.f);
                outH[grow * 128 + nc] = o;
            }
        }
    } else {
#pragma unroll
        for (int tm = 0; tm < 4; ++tm)
#pragma unroll
        for (int r = 0; r < 4; ++r) {
            int ml = wm * 64 + tm * 16 + quad * 4 + r;
            long long grow = rowbase + ml;
            float di = dvec[grow];
            float v = 0.f;
#pragma unroll
            for (int tn = 0; tn < 4; ++tn) {
                int nc = wn * 64 + tn * 16 + ln;
                float hv = hx[grow * 128 + nc];
                v += fabsf(hv - acc[tm][tn][r] * di);
            }
            v += __shfl_xor(v, 1); v += __shfl_xor(v, 2);
            v += __shfl_xor(v, 4); v += __shfl_xor(v, 8);
            if (ln == 0) sred[wn][ml] = v;
        }
        __syncthreads();
        if (tid < 128) outS[rowbase + tid] = sred[0][tid] + sred[1][tid];
    }
}

// ---------------------------------------------------------------------------
// Row-weight GEMM: C[M,128] = rs[row] * (A[M,128] @ W[128,128])  (rs optional)
// ---------------------------------------------------------------------------
__global__ __launch_bounds__(256) void k_gemm_rw(const float* __restrict__ A,
        const float* __restrict__ W, float* __restrict__ C,
        const float* __restrict__ rs) {
    __shared__ float Al[64][68];
    __shared__ float Wl[64][132];
    long long row0 = (long long)blockIdx.x * 64;
    int tid = threadIdx.x, tr = tid >> 4, tc = tid & 15;
    float acc[4][8] = {};
    for (int ch = 0; ch < 2; ++ch) {
        for (int p = tid; p < 1024; p += 256) {
            int r = p >> 4, c4 = p & 15;
            *(float4*)&Al[r][c4 * 4] = *(const float4*)(A + (row0 + r) * 128 + ch * 64 + c4 * 4);
        }
        for (int p = tid; p < 2048; p += 256) {
            int r = p >> 5, c4 = p & 31;
            *(float4*)&Wl[r][c4 * 4] = *(const float4*)(W + (ch * 64 + r) * 128 + c4 * 4);
        }
        __syncthreads();
        for (int k = 0; k < 64; ++k) {
            float4 w0 = *(const float4*)&Wl[k][tc * 8];
            float4 w1 = *(const float4*)&Wl[k][tc * 8 + 4];
            float w[8] = {w0.x, w0.y, w0.z, w0.w, w1.x, w1.y, w1.z, w1.w};
#pragma unroll
            for (int i = 0; i < 4; ++i) {
                float a = Al[tr * 4 + i][k];
#pragma unroll
                for (int j = 0; j < 8; ++j) acc[i][j] = fmaf(a, w[j], acc[i][j]);
            }
        }
        __syncthreads();
    }
#pragma unroll
    for (int i = 0; i < 4; ++i) {
        long long r = row0 + tr * 4 + i;
        float sc = rs ? rs[r] : 1.0f;
        *(float4*)(C + r * 128 + tc * 8)     = make_float4(sc * acc[i][0], sc * acc[i][1], sc * acc[i][2], sc * acc[i][3]);
        *(float4*)(C + r * 128 + tc * 8 + 4) = make_float4(sc * acc[i][4], sc * acc[i][5], sc * acc[i][6], sc * acc[i][7]);
    }
}

// ---------------------------------------------------------------------------
// top-k: bitonic sort of packed keys (~ord(val) << 32 | idx) ascending
//  => value descending, index ascending tiebreak (matches jax.lax.top_k)
// ---------------------------------------------------------------------------
template<int NT, int KSEL>
__global__ __launch_bounds__(256) void k_topk(const float* __restrict__ s, int* __restrict__ idx) {
    __shared__ unsigned long long keys[NT];
    int g = blockIdx.x;
    const float* sg = s + g * NT;
    for (int t = threadIdx.x; t < NT; t += 256) {
        unsigned int b = __float_as_uint(sg[t]);
        unsigned int ord = (b & 0x80000000u) ? ~b : (b | 0x80000000u);
        keys[t] = ((unsigned long long)(~ord) << 32) | (unsigned int)t;
    }
    __syncthreads();
    for (int k = 2; k <= NT; k <<= 1) {
        for (int j = k >> 1; j > 0; j >>= 1) {
            for (int i = threadIdx.x; i < NT; i += 256) {
                int l = i ^ j;
                if (l > i) {
                    bool dir = ((i & k) == 0);
                    unsigned long long a = keys[i], b2 = keys[l];
                    bool sw = dir ? (a > b2) : (a < b2);
                    if (sw) { keys[i] = b2; keys[l] = a; }
                }
            }
            __syncthreads();
        }
    }
    for (int t = threadIdx.x; t < KSEL; t += 256)
        idx[g * KSEL + t] = (int)(keys[t] & 0xffffffffu);
}

// ---------------------------------------------------------------------------
// gather pooled rows + attention dot products
// ---------------------------------------------------------------------------
template<int KK>
__global__ __launch_bounds__(256) void k_gather(const float* __restrict__ h, int srcN,
        const int* __restrict__ idx, const float* __restrict__ atts, const float* __restrict__ attd,
        float* __restrict__ xk, float* __restrict__ as_, float* __restrict__ ad_) {
    int wave = threadIdx.x >> 6, lane = threadIdx.x & 63;
    int r = blockIdx.x * 4 + wave;          // < G*KK
    int g = r / KK;
    int j = idx[r];
    float2 v = *(const float2*)(h + ((long long)g * srcN + j) * 128 + lane * 2);
    *(float2*)(xk + (long long)r * 128 + lane * 2) = v;
    float2 sv = *(const float2*)(atts + lane * 2);
    float2 dv = *(const float2*)(attd + lane * 2);
    float ps = v.x * sv.x + v.y * sv.y;
    float pd = v.x * dv.x + v.y * dv.y;
    ps = wredsum(ps); pd = wredsum(pd);
    if (lane == 0) { as_[r] = ps; ad_[r] = pd; }
}

// ---------------------------------------------------------------------------
// attention: attn = softmax(leaky(as_i + ad_j) + adjSrc[idx_i,idx_j]) + deg epilogue
// ---------------------------------------------------------------------------
template<int KK, int SRCN>
__global__ __launch_bounds__(256) void k_attn(const float* __restrict__ adjSrc,
        const int* __restrict__ idx, const float* __restrict__ as_, const float* __restrict__ ad_,
        float* __restrict__ attn, float* __restrict__ dgo, float* __restrict__ dio) {
    constexpr int E = KK / 64;
    __shared__ int   idxL[KK];
    __shared__ float adL[KK];
    __shared__ float rowL[4][SRCN];
    int bpg = KK / 4;
    int g = blockIdx.x / bpg;
    int wave = threadIdx.x >> 6, lane = threadIdx.x & 63;
    int i = (blockIdx.x % bpg) * 4 + wave;
    for (int t = threadIdx.x; t < KK; t += 256) { idxL[t] = idx[g * KK + t]; adL[t] = ad_[g * KK + t]; }
    __syncthreads();
    int ri = idxL[i];
    const float* arow = adjSrc + ((long long)g * SRCN + ri) * SRCN;
    for (int c = lane; c < SRCN; c += 64) rowL[wave][c] = arow[c];
    float asi = as_[g * KK + i];
    float vals[E];
    float m = -1e30f;
#pragma unroll
    for (int e = 0; e < E; ++e) {
        int j = e * 64 + lane;
        float x = asi + adL[j];
        x = (x >= 0.f) ? x : 0.2f * x;
        x += rowL[wave][idxL[j]];       // LAMB = 1.0
        vals[e] = x; m = fmaxf(m, x);
    }
    m = wredmax(m);
    float S = 0.f;
#pragma unroll
    for (int e = 0; e < E; ++e) { vals[e] = expf(vals[e] - m); S += vals[e]; }
    S = wredsum(S);
    float inv = 1.f / S, rs = 0.f;
    float* orow = attn + ((long long)g * KK + i) * KK;
#pragma unroll
    for (int e = 0; e < E; ++e) { float p = vals[e] * inv; rs += p; orow[e * 64 + lane] = p; }
    rs = wredsum(rs);
    if (lane == 0) { dgo[g * KK + i] = rsqrtf(rs + 1.f); dio[g * KK + i] = 1.f / fmaxf(rs, 1.f); }
}

// ---------------------------------------------------------------------------
// readout: [max over rows, mean over rows] -> (G, 256)
// ---------------------------------------------------------------------------
template<int KK>
__global__ __launch_bounds__(128) void k_readout(const float* __restrict__ xk, float* __restrict__ xo) {
    int g = blockIdx.x, f = threadIdx.x;
    const float* p = xk + (long long)g * KK * 128 + f;
    float m = -1e30f, s = 0.f;
    for (int r = 0; r < KK; ++r) { float v = p[r * 128]; m = fmaxf(m, v); s += v; }
    xo[g * 256 + f] = m;
    xo[g * 256 + 128 + f] = s * (1.0f / KK);
}

// ---------------------------------------------------------------------------
// dense batched agg GEMM: C = A(KKxKK) @ [opt dinv_j *] Y(KKx128)
//  EPI 0: outH = relu(di*C + di^2*hx + bias)   EPI 1: outS_i = sum_f |hx - C*di|
// ---------------------------------------------------------------------------
template<int KK, bool SCALEY, int EPI>
__global__ __launch_bounds__(256) void k_agg(const float* __restrict__ A, const float* __restrict__ Y,
        const float* __restrict__ dg, const float* __restrict__ di_,
        const float* __restrict__ bias, const float* __restrict__ hx,
        float* __restrict__ outH, float* __restrict__ outS) {
    __shared__ float Al[64][68];
    __shared__ float Yl[64][132];
    __shared__ float red[64][17];
    constexpr int RB = KK / 64;
    int g = blockIdx.x / RB;
    int rb = blockIdx.x % RB;
    const float* Ag = A + (long long)g * KK * KK;
    const float* Yg = Y + (long long)g * KK * 128;
    int tid = threadIdx.x, tr = tid >> 4, tc = tid & 15;
    float acc[4][8] = {};
    for (int ch = 0; ch < KK / 64; ++ch) {
        for (int p = tid; p < 1024; p += 256) {
            int r = p >> 4, c4 = p & 15;
            *(float4*)&Al[r][c4 * 4] = *(const float4*)(Ag + (rb * 64 + r) * KK + ch * 64 + c4 * 4);
        }
        for (int p = tid; p < 2048; p += 256) {
            int r = p >> 5, c4 = p & 31;
            float4 v = *(const float4*)(Yg + (ch * 64 + r) * 128 + c4 * 4);
            if (SCALEY) { float sc = dg[g * KK + ch * 64 + r]; v.x *= sc; v.y *= sc; v.z *= sc; v.w *= sc; }
            *(float4*)&Yl[r][c4 * 4] = v;
        }
        __syncthreads();
        for (int k = 0; k < 64; ++k) {
            float4 w0 = *(const float4*)&Yl[k][tc * 8];
            float4 w1 = *(const float4*)&Yl[k][tc * 8 + 4];
            float w[8] = {w0.x, w0.y, w0.z, w0.w, w1.x, w1.y, w1.z, w1.w};
#pragma unroll
            for (int i = 0; i < 4; ++i) {
                float a = Al[tr * 4 + i][k];
#pragma unroll
                for (int j = 0; j < 8; ++j) acc[i][j] = fmaf(a, w[j], acc[i][j]);
            }
        }
        __syncthreads();
    }
    int i0 = rb * 64 + tr * 4;
    if (EPI == 0) {
#pragma unroll
        for (int i = 0; i < 4; ++i) {
            long long gi = (long long)g * KK + i0 + i;
            float d = dg[gi], dd = d * d;
            float4 x0 = *(const float4*)(hx + gi * 128 + tc * 8);
            float4 x1 = *(const float4*)(hx + gi * 128 + tc * 8 + 4);
            float4 b0 = *(const float4*)(bias + tc * 8);
            float4 b1 = *(const float4*)(bias + tc * 8 + 4);
            float4 o0, o1;
            o0.x = fmaxf(fmaf(d, acc[i][0], fmaf(dd, x0.x, b0.x)), 0.f);
            o0.y = fmaxf(fmaf(d, acc[i][1], fmaf(dd, x0.y, b0.y)), 0.f);
            o0.z = fmaxf(fmaf(d, acc[i][2], fmaf(dd, x0.z, b0.z)), 0.f);
            o0.w = fmaxf(fmaf(d, acc[i][3], fmaf(dd, x0.w, b0.w)), 0.f);
            o1.x = fmaxf(fmaf(d, acc[i][4], fmaf(dd, x1.x, b1.x)), 0.f);
            o1.y = fmaxf(fmaf(d, acc[i][5], fmaf(dd, x1.y, b1.y)), 0.f);
            o1.z = fmaxf(fmaf(d, acc[i][6], fmaf(dd, x1.z, b1.z)), 0.f);
            o1.w = fmaxf(fmaf(d, acc[i][7], fmaf(dd, x1.w, b1.w)), 0.f);
            *(float4*)(outH + gi * 128 + tc * 8)     = o0;
            *(float4*)(outH + gi * 128 + tc * 8 + 4) = o1;
        }
    } else {
#pragma unroll
        for (int i = 0; i < 4; ++i) {
            long long gi = (long long)g * KK + i0 + i;
            float d = di_[gi];
            float4 x0 = *(const float4*)(hx + gi * 128 + tc * 8);
            float4 x1 = *(const float4*)(hx + gi * 128 + tc * 8 + 4);
            float p = fabsf(x0.x - acc[i][0] * d) + fabsf(x0.y - acc[i][1] * d)
                    + fabsf(x0.z - acc[i][2] * d) + fabsf(x0.w - acc[i][3] * d)
                    + fabsf(x1.x - acc[i][4] * d) + fabsf(x1.y - acc[i][5] * d)
                    + fabsf(x1.z - acc[i][6] * d) + fabsf(x1.w - acc[i][7] * d);
            red[tr * 4 + i][tc] = p;
        }
        __syncthreads();
        if (tid < 64) {
            float s = 0.f;
#pragma unroll
            for (int t = 0; t < 16; ++t) s += red[tid][t];
            outS[(long long)g * KK + rb * 64 + tid] = s;
        }
    }
}

// ---------------------------------------------------------------------------
// final MLP + softmax, one block per graph
// ---------------------------------------------------------------------------
__global__ __launch_bounds__(128) void k_mlp(const float* __restrict__ x1, const float* __restrict__ x2,
        const float* __restrict__ x3,
        const float* __restrict__ Wl1, const float* __restrict__ bl1,
        const float* __restrict__ Wl2, const float* __restrict__ bl2,
        const float* __restrict__ Wl3, const float* __restrict__ bl3,
        float* __restrict__ out) {
    __shared__ float z[256], z1[128], z2[64], lg[10];
    int g = blockIdx.x, t = threadIdx.x;
    for (int k = t; k < 256; k += 128)
        z[k] = fmaxf(x1[g * 256 + k], 0.f) + fmaxf(x2[g * 256 + k], 0.f) + fmaxf(x3[g * 256 + k], 0.f);
    __syncthreads();
    {
        float acc = bl1[t];
        for (int k = 0; k < 256; ++k) acc = fmaf(z[k], Wl1[k * 128 + t], acc);
        z1[t] = fmaxf(acc, 0.f);
    }
    __syncthreads();
    if (t < 64) {
        float acc = bl2[t];
        for (int k = 0; k < 128; ++k) acc = fmaf(z1[k], Wl2[k * 64 + t], acc);
        z2[t] = fmaxf(acc, 0.f);
    }
    __syncthreads();
    if (t < 10) {
        float acc = bl3[t];
        for (int k = 0; k < 64; ++k) acc = fmaf(z2[k], Wl3[k * 10 + t], acc);
        lg[t] = acc;
    }
    __syncthreads();
    if (t == 0) {
        float m = -1e30f;
        for (int c = 0; c < 10; ++c) m = fmaxf(m, lg[c]);
        float S = 0.f;
        float e[10];
        for (int c = 0; c < 10; ++c) { e[c] = expf(lg[c] - m); S += e[c]; }
        float inv = 1.f / S;
        for (int c = 0; c < 10; ++c) out[g * 10 + c] = e[c] * inv;
    }
}

// ---------------------------------------------------------------------------
extern "C" void kernel_launch(void* const* d_in, const int* in_sizes, int n_in,
                              void* d_out, int out_size, void* d_ws, size_t ws_size,
                              hipStream_t stream) {
    const float* x     = (const float*)d_in[0];
    const float* adj   = (const float*)d_in[1];
    const float* W1    = (const float*)d_in[2];
    const float* b1    = (const float*)d_in[3];
    const float* W2    = (const float*)d_in[4];
    const float* b2    = (const float*)d_in[5];
    const float* W3    = (const float*)d_in[6];
    const float* b3    = (const float*)d_in[7];
    const float* att1s = (const float*)d_in[8];
    const float* att1d = (const float*)d_in[9];
    const float* att2s = (const float*)d_in[10];
    const float* att2d = (const float*)d_in[11];
    const float* Wl1   = (const float*)d_in[12];
    const float* bl1   = (const float*)d_in[13];
    const float* Wl2   = (const float*)d_in[14];
    const float* bl2   = (const float*)d_in[15];
    const float* Wl3   = (const float*)d_in[16];
    const float* bl3   = (const float*)d_in[17];
    float* out = (float*)d_out;

    char* ws = (char*)d_ws;
    // --- workspace layout (~86.2 MB peak, lifetimes annotated) ---
    // T region [0 .. 50,331,648): dxw1T/h1T hi|mid|lo; later xk1/xw2/h2; later xw3/h3/xk2/a2
    unsigned short* Thi  = (unsigned short*)(ws + 0);
    unsigned short* Tmid = (unsigned short*)(ws + 16777216);
    unsigned short* Tlo  = (unsigned short*)(ws + 33554432);
    float* xk1 = (float*)(ws + 0);            // after info1 done
    float* xw2 = (float*)(ws + 16777216);
    float* h2  = (float*)(ws + 33554432);
    float* xk2 = (float*)(ws + 16777216);     // xw2 slot (dead after agg2-epi0)
    float* a2  = (float*)(ws + 25165824);
    float* xw3 = (float*)(ws + 0);            // xk1 slot (dead after readout1)
    float* h3  = (float*)(ws + 8388608);
    // A region [50,331,648 .. 83,886,080): dxw1 -> h1 (in-place) -> a1
    float* dxw1 = (float*)(ws + 50331648);
    float* h1   = dxw1;                       // pointwise in-place epilogue
    float* a1   = dxw1;                       // after h1 dead (post-gather1)
    // smalls
    float* s1      = (float*)(ws + 83886080);
    int*   idx1    = (int*)  (ws + 84148224);
    float* as1     = (float*)(ws + 84279296);
    float* ad1     = (float*)(ws + 84410368);
    float* dinv_g1 = (float*)(ws + 84541440);
    float* dinv_i1 = (float*)(ws + 84803584);
    float* dinv_g2 = (float*)(ws + 85065728);
    float* dinv_i2 = (float*)(ws + 85196800);
    float* x1r     = (float*)(ws + 85327872);
    float* s2      = (float*)(ws + 85458944);
    int*   idx2    = (int*)  (ws + 85590016);
    float* as2     = (float*)(ws + 85655552);
    float* ad2     = (float*)(ws + 85721088);
    float* dinv_g3 = (float*)(ws + 85786624);
    float* dinv_i3 = (float*)(ws + 85852160);
    float* x2r     = (float*)(ws + 85917696);
    float* x3r     = (float*)(ws + 86048768);

    // stage 1: full graph (N=512), adjacency aggregations via bf16-split MFMA
    k_prep<<<Gg * N1 / 4, 256, 0, stream>>>(adj, dinv_g1, dinv_i1);
    k_gemm_rw<<<Gg * N1 / 64, 256, 0, stream>>>(x, W1, dxw1, dinv_g1);
    k_tsplit<<<Gg * 16, 256, 0, stream>>>(dxw1, Thi, Tmid, Tlo);
    k_aggmm<0><<<Gg * 4, 256, 0, stream>>>(adj, Thi, Tmid, Tlo, dinv_g1, dxw1, b1, h1, nullptr);
    k_tsplit<<<Gg * 16, 256, 0, stream>>>(h1, Thi, Tmid, Tlo);
    k_aggmm<1><<<Gg * 4, 256, 0, stream>>>(adj, Thi, Tmid, Tlo, dinv_i1, h1, nullptr, nullptr, s1);
    k_topk<N1, K1><<<Gg, 256, 0, stream>>>(s1, idx1);
    k_gather<K1><<<Gg * K1 / 4, 256, 0, stream>>>(h1, N1, idx1, att1s, att1d, xk1, as1, ad1);
    k_readout<K1><<<Gg, 128, 0, stream>>>(xk1, x1r);
    k_attn<K1, N1><<<Gg * K1 / 4, 256, 0, stream>>>(adj, idx1, as1, ad1, a1, dinv_g2, dinv_i2);

    // stage 2: pooled graph (K1=256), dense attention adjacency a1
    k_gemm_rw<<<Gg * K1 / 64, 256, 0, stream>>>(xk1, W2, xw2, nullptr);
    k_agg<K1, true, 0><<<Gg * (K1 / 64), 256, 0, stream>>>(a1, xw2, dinv_g2, dinv_i2, b2, xw2, h2, nullptr);
    k_agg<K1, false, 1><<<Gg * (K1 / 64), 256, 0, stream>>>(a1, h2, dinv_g2, dinv_i2, b2, h2, nullptr, s2);
    k_topk<K1, K2><<<Gg, 256, 0, stream>>>(s2, idx2);
    k_gather<K2><<<Gg * K2 / 4, 256, 0, stream>>>(h2, K1, idx2, att2s, att2d, xk2, as2, ad2);
    k_readout<K2><<<Gg, 128, 0, stream>>>(xk2, x2r);
    k_attn<K2, K1><<<Gg * K2 / 4, 256, 0, stream>>>(a1, idx2, as2, ad2, a2, dinv_g3, dinv_i3);

    // stage 3: pooled graph (K2=128), dense attention adjacency a2
    k_gemm_rw<<<Gg * K2 / 64, 256, 0, stream>>>(xk2, W3, xw3, nullptr);
    k_agg<K2, true, 0><<<Gg * (K2 / 64), 256, 0, stream>>>(a2, xw3, dinv_g3, dinv_i3, b3, xw3, h3, nullptr);
    k_readout<K2><<<Gg, 128, 0, stream>>>(h3, x3r);

    // final MLP
    k_mlp<<<Gg, 128, 0, stream>>>(x1r, x2r, x3r, Wl1, bl1, Wl2, bl2, Wl3, bl3, out);
}